// Round 12
// baseline (85.911 us; speedup 1.0000x reference)
//
#include <hip/hip_runtime.h>

// PolyLinear: out[i] = b + sum_j W[j] * prod_k x_aug[i, idx[j,k]]
// Deterministic lex-order enumeration: deg1 W[0..31], deg2 W[32..559] (a<=b),
// deg3 W[560..6543] (a<=b<=c). Factorization per row:
//   acc = sum_a W1[a]*x_a
//       + sum_{a<=b} (x_a*x_b) * ( W2[a,b] + sum_{c>=b} W3[a,b,c]*x_c )
//
// V12. Evidence through 11 rounds:
//   - R=2 rows/thread is the spill-free max (R=4 spilled at every VGPR cap).
//   - Weights via compiler-scalarized SMEM: drain-bound (44us, 15% VALU).
//   - V11 (512-thr, 8 waves, NPART=8, all-LDS weights) sits AT the LDS-port
//     structural floor: 6544 weights/CU/128rows = ~2000 LDS reads ~ 8.4us
//     issue, while VALU needs only ~3us and VMEM sits idle after X-load.
// V12 splits weight delivery across both pipes: waves 0-3 read their parts
// from LDS (ds_read_b128); waves 4-7 read theirs from global W via an
// OPAQUE VGPR offset (asm "+v") so the compiler cannot scalarize to s_load
// (the drain trap) and must emit pipelined global_load_dwordx4 — uniform
// address = single broadcast transaction, L1-resident (W = 26KB).
// Per-CU: LDS ~820 b128 (3.4us) || VMEM ~820 dwordx4 (~3.5-4us) || VALU 3us
// -> kernel floor ~6-8us (vs 12.5 measured for V11).
// LDS staging shrinks to the prefix waves 0-3 touch: parts 0-3 own pairs
// with cum3 < 2992, whose deg3 runs end at W-index <= 3582 -> stage 3584.
// Spill tripwire: WRITE_SIZE must stay ~0.15MB; if it balloons, revert V11.

#define NPART 8
#define TOTAL3 5984

__device__ __forceinline__ constexpr int off2(int a, int b) {
    // deg2 base 32; pairs (a<=b) lex order
    return 32 + 32 * a - (a * (a - 1)) / 2 + (b - a);
}

__device__ __forceinline__ constexpr int off3(int a, int b, int c) {
    // deg3 base 560; triples (a<=b<=c) lex order.
    // g3[a] = #triples with first index < a
    constexpr int g3[32] = {
        0,    528,  1024, 1489, 1924, 2330, 2708, 3059,
        3384, 3684, 3960, 4213, 4444, 4654, 4844, 5015,
        5168, 5304, 5424, 5529, 5620, 5698, 5764, 5819,
        5864, 5900, 5928, 5949, 5964, 5974, 5980, 5983};
    return 560 + g3[a] + 32 * (b - a) - ((b * (b - 1)) / 2 - (a * (a - 1)) / 2) + (c - b);
}

// #deg3 triples strictly before pair (a,b)'s c-run in lex order
__device__ __forceinline__ constexpr int cum3(int a, int b) {
    return off3(a, b, b) - 560;
}

// Balanced static ownership of pair (a,b): parts get ~equal deg3-FMA counts.
__device__ __forceinline__ constexpr int owner_of(int a, int b) {
    return (cum3(a, b) * NPART) / TOTAL3;  // monotone, 0..NPART-1
}

template <int PART>
__device__ __forceinline__ void eval_part2(const float* __restrict__ Wsrc,
                                           const float (&x0)[32],
                                           const float (&x1)[32],
                                           float& r0, float& r1) {
    float a0 = 0.0f, a1 = 0.0f;
#pragma unroll
    for (int a = 0; a < 32; ++a) {
#pragma unroll
        for (int b = a; b < 32; ++b) {
            if (owner_of(a, b) == PART) {  // compile-time filter
                if (a == b) {  // attach deg1 term for feature a here
                    const float w1 = Wsrc[a];
                    a0 = __builtin_fmaf(w1, x0[a], a0);
                    a1 = __builtin_fmaf(w1, x1[a], a1);
                }
                const float w2 = Wsrc[off2(a, b)];  // deg2 weight seeds chains
                float s0 = w2, s1 = w2;
#pragma unroll
                for (int c = b; c < 32; ++c) {
                    const float w = Wsrc[off3(a, b, c)];  // 1 read, 2 FMAs
                    s0 = __builtin_fmaf(w, x0[c], s0);
                    s1 = __builtin_fmaf(w, x1[c], s1);
                }
                a0 = __builtin_fmaf(x0[a] * x0[b], s0, a0);
                a1 = __builtin_fmaf(x1[a] * x1[b], s1, a1);
            }
        }
    }
    r0 = a0;
    r1 = a1;
}

// Block: 512 threads = 8 waves. Wave w computes part w of the SAME 128 rows
// (lane owns rows base+lane, base+64+lane). Waves 0-3: weights from LDS;
// waves 4-7: weights from global (opaque VGPR offset -> VMEM, not SMEM).
// LDS reduce across waves, coalesced store. grid = rows/128 = 256 = 1/CU.
__global__ __launch_bounds__(512) void PolyLinear_40218073760341_kernel(
    const float* __restrict__ X,   // (rows, 32)
    const float* __restrict__ W,   // (6544,)
    const float* __restrict__ Bp,  // (1,)
    float* __restrict__ out)       // (rows,)
{
    const int lane = threadIdx.x & 63;
    const int wave = threadIdx.x >> 6;  // part id 0..7
    const long base = (long)blockIdx.x * 128;

    __shared__ float Wl[3584];         // 14.3 KB: prefix used by waves 0-3
    __shared__ float partial[8][128];  // 4 KB reduce buffer

    // Stage W[0:3584) -> LDS (coalesced float4; 896 vec4 over 512 threads)
    {
        const float4* Wg4 = (const float4*)W;
        float4* Wd = (float4*)Wl;
        for (int i = threadIdx.x; i < 896; i += 512) Wd[i] = Wg4[i];
    }

    // Load this lane's 2 rows (all waves read the same 128 rows; L1-hit
    // after the first wave touches them).
    float x0[32], x1[32];
    {
        const float4* p0 = (const float4*)(X + (base + lane) * 32);
        const float4* p1 = (const float4*)(X + (base + 64 + lane) * 32);
#pragma unroll
        for (int i = 0; i < 8; ++i) {
            const float4 a = p0[i];
            x0[4 * i + 0] = a.x; x0[4 * i + 1] = a.y;
            x0[4 * i + 2] = a.z; x0[4 * i + 3] = a.w;
            const float4 b = p1[i];
            x1[4 * i + 0] = b.x; x1[4 * i + 1] = b.y;
            x1[4 * i + 2] = b.z; x1[4 * i + 3] = b.w;
        }
    }
    __syncthreads();  // Wl ready

    // Opaque zero offset in a VGPR: blocks SMEM scalarization of the
    // uniform W reads for waves 4-7, forcing the pipelined VMEM path.
    int zoff = 0;
    asm volatile("" : "+v"(zoff));
    const float* Wg = W + zoff;

    float r0 = 0.0f, r1 = 0.0f;
    switch (wave) {
        case 0: eval_part2<0>(Wl, x0, x1, r0, r1); break;
        case 1: eval_part2<1>(Wl, x0, x1, r0, r1); break;
        case 2: eval_part2<2>(Wl, x0, x1, r0, r1); break;
        case 3: eval_part2<3>(Wl, x0, x1, r0, r1); break;
        case 4: eval_part2<4>(Wg, x0, x1, r0, r1); break;
        case 5: eval_part2<5>(Wg, x0, x1, r0, r1); break;
        case 6: eval_part2<6>(Wg, x0, x1, r0, r1); break;
        case 7: eval_part2<7>(Wg, x0, x1, r0, r1); break;
    }

    partial[wave][lane] = r0;
    partial[wave][64 + lane] = r1;
    __syncthreads();

    if (threadIdx.x < 128) {
        float r = Bp[0];
#pragma unroll
        for (int w = 0; w < 8; ++w) r += partial[w][threadIdx.x];
        out[base + threadIdx.x] = r;
    }
}

extern "C" void kernel_launch(void* const* d_in, const int* in_sizes, int n_in,
                              void* d_out, int out_size, void* d_ws, size_t ws_size,
                              hipStream_t stream) {
    const float* X  = (const float*)d_in[0];  // (32768, 32) fp32
    const float* W  = (const float*)d_in[1];  // (1, 6544) fp32
    const float* Bp = (const float*)d_in[2];  // (1,) fp32
    // d_in[3] = idx — deterministic, unused.
    float* out = (float*)d_out;

    const int rows = in_sizes[0] / 32;  // 32768
    const int grid = rows / 128;        // 256 blocks of 512 threads
    PolyLinear_40218073760341_kernel<<<grid, 512, 0, stream>>>(X, W, Bp, out);
}